// Round 1
// baseline (107.310 us; speedup 1.0000x reference)
//
#include <hip/hip_runtime.h>
#include <hip/hip_bf16.h>

// SparseGCM: 2-layer causal-window GCN on MI355X.
// Key insight: edges are j->i for j in [i-16, i) per batch; edge weights
// normalize to exactly 1.0 in forward. So "gather + segment_sum" == 16-wide
// sliding window sum over time. Only output rows i in [512,640) are needed,
// so layer1 computes rows [496,640) and node rows [480,640) are touched.

namespace {

constexpr int BQ    = 64;    // batch
constexpr int T0C   = 512;
constexpr int TAUC  = 128;
constexpr int NTOTC = 640;
constexpr int FEATC = 256;

constexpr int N1 = 160;   // nbuf rows per batch: i in [480,640)
constexpr int M1 = 144;   // layer-1 rows per batch: i in [496,640)
constexpr int M2 = 128;   // layer-2 rows per batch: i in [512,640)

// ---------------------------------------------------------------------------
// prep1: nbuf[b][ii][f] = node row i=480+ii (from nodes, or x when i>=512)
//        sbuf[b][t][f]  = sum_{j=i-16}^{i-1} n[b][j][f] for i=496+t
// One block per batch, one thread per feature. Running-window O(1)/step.
// ---------------------------------------------------------------------------
__global__ void prep1_kernel(const float* __restrict__ x,
                             const float* __restrict__ nodes,
                             float* __restrict__ nbuf,
                             float* __restrict__ sbuf) {
  const int b = blockIdx.x;
  const int f = threadIdx.x;
  const float* xb = x     + ((size_t)b * TAUC)  * FEATC + f;
  const float* nb = nodes + ((size_t)b * NTOTC) * FEATC + f;
  float* no = nbuf + ((size_t)b * N1) * FEATC + f;
  float* so = sbuf + ((size_t)b * M1) * FEATC + f;

  float win = 0.f;
  #pragma unroll
  for (int ii = 0; ii < 16; ++ii) {          // i = 480..495, all < T0 -> nodes
    const float v = nb[(480 + ii) * FEATC];
    no[ii * FEATC] = v;
    win += v;
  }
  for (int t = 0; t < M1; ++t) {             // i = 496 + t
    so[t * FEATC] = win;                     // sum over [i-16, i)
    const int i = 496 + t;
    const float v = (i < T0C) ? nb[i * FEATC] : xb[(i - T0C) * FEATC];
    no[(16 + t) * FEATC] = v;
    const float old = no[t * FEATC];         // row (i-16)-480 = t (same thread wrote it)
    win += v - old;
  }
}

// ---------------------------------------------------------------------------
// prep2: sh1[b][t][f] = sum_{ii=t}^{t+15} h1[b][ii][f]   (i = 512+t window)
// ---------------------------------------------------------------------------
__global__ void prep2_kernel(const float* __restrict__ h1,
                             float* __restrict__ sh1) {
  const int b = blockIdx.x;
  const int f = threadIdx.x;
  const float* hp = h1  + ((size_t)b * M1) * FEATC + f;
  float*       sp = sh1 + ((size_t)b * M2) * FEATC + f;
  float win = 0.f;
  #pragma unroll
  for (int ii = 0; ii < 16; ++ii) win += hp[ii * FEATC];
  for (int t = 0; t < M2; ++t) {
    sp[t * FEATC] = win;
    win += hp[(16 + t) * FEATC] - hp[t * FEATC];
  }
}

// ---------------------------------------------------------------------------
// Fused dual-GEMM + bias + tanh:
//   C[r] = tanh(A1row(r) @ Ws + A2[r] @ Wn + bias),  K=256 each, N=256.
// Treated as one [M,512] @ [512,256] with concatenated A and W.
// A1 rows are remapped: r -> (r/rpbA)*bpbA + r%rpbA + offA (buffer has extra
// leading rows per batch). A2 rows map 1:1.
// fp32, 64x64 block tile, BK=16, 256 threads, 4x4 microtile.
// ---------------------------------------------------------------------------
__global__ __launch_bounds__(256) void gemm2_tanh(
    const float* __restrict__ A1, const float* __restrict__ A2,
    const float* __restrict__ Ws, const float* __restrict__ Wn,
    const float* __restrict__ bias, float* __restrict__ C,
    int rpbA, int bpbA, int offA) {
  __shared__ __align__(16) float As[16][68];  // [k][m], +4 pad kills write conflicts
  __shared__ __align__(16) float Bs[16][68];  // [k][n]

  const int t  = threadIdx.x;
  const int m0 = blockIdx.x * 64;
  const int n0 = blockIdx.y * 64;
  const int tn = t & 15, tm = t >> 4;       // compute thread grid 16x16
  const int arow = t >> 2, akq = t & 3;     // A-tile loader: 64 rows x 4 quads
  const int brow = t >> 4, bnq = t & 15;    // B-tile loader: 16 rows x 16 quads

  const int rA = m0 + arow;
  const int r1 = (rA / rpbA) * bpbA + (rA % rpbA) + offA;
  const float* a1p = A1 + (size_t)r1 * FEATC + akq * 4;
  const float* a2p = A2 + (size_t)rA * FEATC + akq * 4;

  float acc[4][4] = {};

  for (int ks = 0; ks < 32; ++ks) {
    const int k0 = ks * 16;
    const float* ap;
    const float* wp;
    int kk;
    if (k0 < FEATC) { ap = a1p; wp = Ws; kk = k0; }
    else            { ap = a2p; wp = Wn; kk = k0 - FEATC; }

    const float4 av = *(const float4*)(ap + kk);
    const float4 bv = *(const float4*)(wp + (size_t)(kk + brow) * FEATC + n0 + bnq * 4);

    __syncthreads();
    As[akq * 4 + 0][arow] = av.x;
    As[akq * 4 + 1][arow] = av.y;
    As[akq * 4 + 2][arow] = av.z;
    As[akq * 4 + 3][arow] = av.w;
    *(float4*)&Bs[brow][bnq * 4] = bv;
    __syncthreads();

    #pragma unroll
    for (int k = 0; k < 16; ++k) {
      const float4 a  = *(const float4*)&As[k][tm * 4];
      const float4 bb = *(const float4*)&Bs[k][tn * 4];
      const float aa[4]  = {a.x, a.y, a.z, a.w};
      const float bbv[4] = {bb.x, bb.y, bb.z, bb.w};
      #pragma unroll
      for (int i = 0; i < 4; ++i)
        #pragma unroll
        for (int j = 0; j < 4; ++j)
          acc[i][j] = fmaf(aa[i], bbv[j], acc[i][j]);
    }
  }

  const float4 bsv = *(const float4*)(bias + n0 + tn * 4);
  const float bias4[4] = {bsv.x, bsv.y, bsv.z, bsv.w};
  #pragma unroll
  for (int i = 0; i < 4; ++i) {
    float4 o;
    o.x = tanhf(acc[i][0] + bias4[0]);
    o.y = tanhf(acc[i][1] + bias4[1]);
    o.z = tanhf(acc[i][2] + bias4[2]);
    o.w = tanhf(acc[i][3] + bias4[3]);
    *(float4*)(C + (size_t)(m0 + tm * 4 + i) * FEATC + n0 + tn * 4) = o;
  }
}

}  // namespace

extern "C" void kernel_launch(void* const* d_in, const int* in_sizes, int n_in,
                              void* d_out, int out_size, void* d_ws, size_t ws_size,
                              hipStream_t stream) {
  const float* x     = (const float*)d_in[0];
  const float* nodes = (const float*)d_in[1];
  // d_in[2] = edge_weight: forward value is ew/ew == 1.0 -> unused.
  const float* W1s = (const float*)d_in[3];
  const float* W1n = (const float*)d_in[4];
  const float* b1  = (const float*)d_in[5];
  const float* W2s = (const float*)d_in[6];
  const float* W2n = (const float*)d_in[7];
  const float* b2  = (const float*)d_in[8];
  // d_in[9..12] = edge_src, edge_dst, T0, tau: structure is static -> unused.
  float* out = (float*)d_out;

  // workspace layout (floats)
  const size_t nbuf_sz = (size_t)BQ * N1 * FEATC;  // 2,621,440
  const size_t sbuf_sz = (size_t)BQ * M1 * FEATC;  // 2,359,296
  const size_t h1_sz   = (size_t)BQ * M1 * FEATC;  // 2,359,296
  const size_t sh1_sz  = (size_t)BQ * M2 * FEATC;  // 2,097,152
  const size_t need = (nbuf_sz + sbuf_sz + h1_sz + sh1_sz) * sizeof(float);
  if (ws_size < need) return;  // signal: absmax stays at poison level

  float* ws   = (float*)d_ws;
  float* nbuf = ws;
  float* sbuf = nbuf + nbuf_sz;
  float* h1   = sbuf + sbuf_sz;
  float* sh1  = h1 + h1_sz;

  prep1_kernel<<<BQ, 256, 0, stream>>>(x, nodes, nbuf, sbuf);
  gemm2_tanh<<<dim3((BQ * M1) / 64, FEATC / 64), 256, 0, stream>>>(
      nbuf, sbuf, W1s, W1n, b1, h1, M1, N1, 16);
  prep2_kernel<<<BQ, 256, 0, stream>>>(h1, sh1);
  gemm2_tanh<<<dim3((BQ * M2) / 64, FEATC / 64), 256, 0, stream>>>(
      h1, sh1, W2s, W2n, b2, out, M2, M1, 16);
}